// Round 2
// baseline (330.017 us; speedup 1.0000x reference)
//
#include <hip/hip_runtime.h>
#include <cstdint>

// Column1: 512 independent (32x2048)@(2048x32) fp32 GEMMs + per-branch kWTA epilogue.
// R2: occupancy fix. R1 had 64KB LDS -> 2 blocks/CU -> 20% occupancy -> 2.65 TB/s.
// Now: CHUNK=64 (32KB LDS), L split 4-ways -> 2048 blocks, ~5 blocks/CU resident.
// Partial (32x32) sums per (branch,split) -> d_ws; second kernel reduces + kWTA.

#define RFN 512
#define TN  32
#define KN  32
#define LN  2048
#define SPLIT 4
#define LSEG (LN / SPLIT)    // 512
#define CHUNK 64
#define NITER (LSEG / CHUNK) // 8

__global__ __launch_bounds__(256, 5) void column1_gemm(
    const float* __restrict__ rec,   // (T=32, C=1, RF=512, L=2048)
    const float* __restrict__ wgt,   // (RF=512, K=32, C=1, L=2048)
    float* __restrict__ wsout)       // (RF, SPLIT, 32*32) partial potentials
{
    __shared__ __align__(16) float lds[2 * 64 * CHUNK];  // 32768 B
    const int bs   = blockIdx.x;
    const int r    = bs >> 2;        // branch
    const int sseg = bs & 3;         // l-segment
    const int l0   = sseg * LSEG;
    const int tid  = threadIdx.x;
    const int lane = tid & 63;
    const int wv   = tid >> 6;       // wave 0..3: splits chunk's 16 quads 4-ways
    const int tg   = lane >> 3;      // 0..7 : owns t in {tg, tg+8, tg+16, tg+24}
    const int kg   = lane & 7;       // 0..7 : owns k in {kg, kg+8, kg+16, kg+24}

    // ---- staging: 4 float4/thread; rows r0+16s (0..31 rec-t, 32..63 wgt-k), quad c4
    const int c4 = tid & 15;         // quad within 64 floats
    const int r0 = tid >> 4;         // 0..15
    const float* gsrc[4];
    int ldoff[4];
#pragma unroll
    for (int s = 0; s < 4; ++s) {
        const int row = r0 + 16 * s;                // 0..63
        const float* g;
        if (row < 32) g = rec + ((size_t)(row * RFN + r)) * LN + l0 + (c4 << 2);
        else          g = wgt + ((size_t)(r * KN + (row - 32))) * LN + l0 + (c4 << 2);
        gsrc[s]  = g;
        // XOR swizzle: quad c4 stored at c4 ^ (row&15) -> conflict-free b128 reads, no pad
        ldoff[s] = row * CHUNK + ((c4 ^ (row & 15)) << 2);
    }

    float4 stage[4];
#pragma unroll
    for (int s = 0; s < 4; ++s) stage[s] = *(const float4*)gsrc[s];

    float acc[4][4];
#pragma unroll
    for (int jt = 0; jt < 4; ++jt)
#pragma unroll
        for (int jk = 0; jk < 4; ++jk) acc[jt][jk] = 0.0f;

    int p = 0;
    for (int it = 0; it < NITER; ++it) {
        float* buf = lds + p * (64 * CHUNK);
#pragma unroll
        for (int s = 0; s < 4; ++s) *(float4*)(buf + ldoff[s]) = stage[s];
        __syncthreads();                             // double-buffer: one barrier/chunk
        if (it + 1 < NITER) {
#pragma unroll
            for (int s = 0; s < 4; ++s) {
                gsrc[s] += CHUNK;
                stage[s] = *(const float4*)gsrc[s];  // next chunk in flight during compute
            }
        }
        const float* rs = buf;
        const float* wsh = buf + 32 * CHUNK;
#pragma unroll
        for (int q = 0; q < 4; ++q) {
            const int qg = (wv << 2) + q;            // this wave's l-quad (0..15)
            float4 a[4], b[4];
#pragma unroll
            for (int j = 0; j < 4; ++j) {
                const int row = tg + 8 * j;
                a[j] = *(const float4*)(rs + row * CHUNK + ((qg ^ (row & 15)) << 2));
            }
#pragma unroll
            for (int j = 0; j < 4; ++j) {
                const int row = kg + 8 * j;
                b[j] = *(const float4*)(wsh + row * CHUNK + ((qg ^ (row & 15)) << 2));
            }
#pragma unroll
            for (int jt = 0; jt < 4; ++jt)
#pragma unroll
                for (int jk = 0; jk < 4; ++jk) {
                    float v0 = fmaf(a[jt].x, b[jk].x, acc[jt][jk]);
                    v0 = fmaf(a[jt].y, b[jk].y, v0);
                    v0 = fmaf(a[jt].z, b[jk].z, v0);
                    acc[jt][jk] = fmaf(a[jt].w, b[jk].w, v0);
                }
        }
        p ^= 1;
    }

    // ---- cross-wave reduction into buffer-0 region (final compute read buffer 1 -> safe)
    float* red = lds;                                // 4 x 1024 floats = 16 KB
#pragma unroll
    for (int jt = 0; jt < 4; ++jt)
#pragma unroll
        for (int jk = 0; jk < 4; ++jk)
            red[(wv << 10) + (tg + 8 * jt) * 32 + (kg + 8 * jk)] = acc[jt][jk];
    __syncthreads();

    // partial potential (t,k) flat o = tid*4+e -> ws[(r*4+sseg)*1024 + o]
    const int o = tid << 2;
    float4 p0 = *(const float4*)(red + o);
    float4 p1 = *(const float4*)(red + 1024 + o);
    float4 p2 = *(const float4*)(red + 2048 + o);
    float4 p3 = *(const float4*)(red + 3072 + o);
    float4 pv;
    pv.x = p0.x + p1.x + p2.x + p3.x;
    pv.y = p0.y + p1.y + p2.y + p3.y;
    pv.z = p0.z + p1.z + p2.z + p3.z;
    pv.w = p0.w + p1.w + p2.w + p3.w;
    *(float4*)(wsout + (size_t)(r * SPLIT + sseg) * 1024 + o) = pv;
}

__global__ __launch_bounds__(256) void column1_epilogue(
    const float* __restrict__ wsin,  // (RF, SPLIT, 1024)
    float* __restrict__ out)         // (T=32, 1, K=32, RF=512)
{
    __shared__ float thr_s[32 * 33];
    __shared__ float nspk_s[32], vals_s[32], cand_s[32], tot_s[32], mask_s[32];
    const int r   = blockIdx.x;
    const int tid = threadIdx.x;
    const float* base = wsin + (size_t)r * (SPLIT * 1024);

    const int o = tid << 2;
    float4 p0 = *(const float4*)(base + o);
    float4 p1 = *(const float4*)(base + 1024 + o);
    float4 p2 = *(const float4*)(base + 2048 + o);
    float4 p3 = *(const float4*)(base + 3072 + o);
    float pv[4] = { p0.x + p1.x + p2.x + p3.x,
                    p0.y + p1.y + p2.y + p3.y,
                    p0.z + p1.z + p2.z + p3.z,
                    p0.w + p1.w + p2.w + p3.w };
#pragma unroll
    for (int e = 0; e < 4; ++e) {
        const int oo = o + e;
        const float th = (pv[e] > 20.0f) ? pv[e] : 0.0f;  // sf.fire: strictly greater
        thr_s[(oo >> 5) * 33 + (oo & 31)] = th;
    }
    __syncthreads();

    if (tid < 32) {
        const int k = tid;
        int ns = 0;
        for (int t = 0; t < 32; ++t) ns += (thr_s[t * 33 + k] > 0.0f) ? 1 : 0;
        int first = 32 - ns; if (first > 31) first = 31;   // clip(T - nspk, 0, T-1)
        const float vf = thr_s[first * 33 + k];
        nspk_s[k] = (float)ns;
        vals_s[k] = vf;
        cand_s[k] = (ns > 0) ? vf : 0.0f;                  // max_t spikes*vals per k
        mask_s[k] = 0.0f;
    }
    __syncthreads();

    if (tid == 0) {
        float vm = 0.0f;
        for (int k = 0; k < 32; ++k) vm = fmaxf(vm, cand_s[k]);
        const float v = vm * 32.0f;                        // trunc.max() * T
        for (int k = 0; k < 32; ++k) tot_s[k] = nspk_s[k] * (vals_s[k] + v);
        // top-4, ties -> lower index (matches lax.top_k); winner valid iff total != 0
        for (int sel = 0; sel < 4; ++sel) {
            int best = 0; float bv = -1.0f;
            for (int k = 0; k < 32; ++k) {
                const float tv = tot_s[k];
                if (tv > bv) { bv = tv; best = k; }
            }
            if (bv > 0.0f) mask_s[best] = 1.0f;
            tot_s[best] = -1.0f;
        }
    }
    __syncthreads();

#pragma unroll
    for (int e = 0; e < 4; ++e) {
        const int oo = o + e;
        const int t = oo >> 5, k = oo & 31;
        out[(size_t)t * (KN * RFN) + k * RFN + r] =
            (thr_s[t * 33 + k] > 0.0f && mask_s[k] > 0.0f) ? 1.0f : 0.0f;
    }
}

extern "C" void kernel_launch(void* const* d_in, const int* in_sizes, int n_in,
                              void* d_out, int out_size, void* d_ws, size_t ws_size,
                              hipStream_t stream) {
    const float* rec = (const float*)d_in[0];   // rec_field (32,1,512,2048)
    const float* wgt = (const float*)d_in[1];   // W         (512,32,1,2048)
    // d_in[2] = reward: unused by the forward output
    float* out = (float*)d_out;                 // (32,1,32,512)
    float* ws  = (float*)d_ws;                  // needs 512*4*1024*4 B = 8.4 MB
    column1_gemm<<<dim3(RFN * SPLIT), dim3(256), 0, stream>>>(rec, wgt, ws);
    column1_epilogue<<<dim3(RFN), dim3(256), 0, stream>>>(ws, out);
}